// Round 3
// baseline (873.518 us; speedup 1.0000x reference)
//
#include <hip/hip_runtime.h>
#include <hip/hip_cooperative_groups.h>

namespace cg = cooperative_groups;

#define NN 4096
#define MM 8192
#define GG 8
#define HH 128
#define NDD 16
#define EE 131072
#define CBLK 64            // cond partial blocks
#define COBJ (MM / CBLK)   // 128 objects per cond block
#define WBLK 8             // W1p gemm blocks (2 rows each)
#define CAP 96             // padded CSR row capacity (Poisson(32): P(deg>96) ~ 1e-20)
#define NBLK 1024          // cooperative grid: 4 blocks/CU x 256 CUs

typedef float nt_f4 __attribute__((ext_vector_type(4)));

struct Prm {
    const float* x;
    const int *e_src, *e_dst, *timestep, *bm, *nuc, *central, *backbone;
    const float *obj_x, *obj_pos;
    const int* obj_batch;
    const float *Wn, *bn, *Wc, *bc, *Wt, *bt, *Wc1, *b1, *Wc2, *b2, *Wo, *bo, *we, *be;
    float *bufA, *bufB, *W1p, *c1g, *partial, *pcnt, *sl, *sr;
    int *cnt, *col_idx;
    float *out_pred, *out_edges;
};

// 18.5 KB max -> >=4 blocks/CU with huge margin (coop co-residency guaranteed)
union SMem {
    struct { float ls[GG * NDD]; float lc[GG]; } cond;
    struct { float te[HH], pool[HH], v2[HH], red[2][HH], s16[NDD], cinv; } c1;
    struct { float hr[4][HH]; float wsm[32 * HH]; } conv;  // 2KB + 16KB
};

// ---------- PH0: zero cnt (0..3) | cond partials (4..67) | W1p (68..75) ----------
__device__ __forceinline__ void ph0(const Prm& p, SMem& sm, int b, int t) {
    if (b < 4) {
        ((int4*)p.cnt)[b * 256 + t] = make_int4(0, 0, 0, 0);
        return;
    }
    if (b < 4 + CBLK) {
        int cb = b - 4;
        if (t < GG * NDD) sm.cond.ls[t] = 0.f;
        if (t < GG) sm.cond.lc[t] = 0.f;
        __syncthreads();
        int d = t & 15, oi = t >> 4;
        int base = cb * COBJ;
#pragma unroll
        for (int pass = 0; pass < COBJ / 16; pass++) {
            int o = base + pass * 16 + oi;
            int nv = p.nuc[o];
            bool isb = (p.backbone[o] == 0);
            bool cond = (nv == 0) || ((p.central[o] != 0) && isb) || ((nv == 2) && isb);
            if (cond) {
                float v = (d < 13) ? p.obj_x[o * 13 + d] : p.obj_pos[o * 3 + (d - 13)];
                int g = p.obj_batch[o];
                atomicAdd(&sm.cond.ls[g * NDD + d], v);
                if (d == 0) atomicAdd(&sm.cond.lc[g], 1.f);
            }
        }
        __syncthreads();
        if (t < GG * NDD) p.partial[cb * (GG * NDD) + t] = sm.cond.ls[t];
        if (t < GG) p.pcnt[cb * GG + t] = sm.cond.lc[t];
        return;
    }
    if (b < 4 + CBLK + WBLK) {
        int wb = b - (4 + CBLK);
        int j = t & 127, a = wb * 2 + (t >> 7);
        float acc = 0.f;
        for (int k = 0; k < HH; k++) acc += p.Wn[a * HH + k] * p.Wc1[k * HH + j];
        p.W1p[a * HH + j] = acc;
    }
}

// ---------- PH1: padded-CSR scatter (0..127) | c1 per-graph (128..135) ----------
__device__ __forceinline__ void ph1(const Prm& p, SMem& sm, int b, int t) {
    if (b < 128) {
        int i4 = b * 256 + t;  // 32768 int4 = 131072 edges
        int4 d4 = ((const int4*)p.e_dst)[i4];
        int4 s4 = ((const int4*)p.e_src)[i4];
        int q;
        q = atomicAdd(&p.cnt[d4.x], 1); if (q < CAP) p.col_idx[d4.x * CAP + q] = s4.x;
        q = atomicAdd(&p.cnt[d4.y], 1); if (q < CAP) p.col_idx[d4.y * CAP + q] = s4.y;
        q = atomicAdd(&p.cnt[d4.z], 1); if (q < CAP) p.col_idx[d4.z * CAP + q] = s4.z;
        q = atomicAdd(&p.cnt[d4.w], 1); if (q < CAP) p.col_idx[d4.w * CAP + q] = s4.w;
        return;
    }
    if (b >= 136) return;
    int g = b - 128;
    int j = t & 127, kh = t >> 7;
    if (t >= 128) {
        int j2 = t - 128;
        float tv = (float)p.timestep[g];
        float f = expf(-logf(10000.f) * (float)(j2 & 63) / 64.f);
        sm.c1.te[j2] = (j2 < 64) ? cosf(tv * f) : sinf(tv * f);
    } else if (t < NDD) {
        float s = 0.f;
        for (int q = 0; q < CBLK; q++) s += p.partial[q * (GG * NDD) + g * NDD + t];
        sm.c1.s16[t] = s;
    } else if (t == NDD) {
        float c = 0.f;
        for (int q = 0; q < CBLK; q++) c += p.pcnt[q * GG + g];
        sm.c1.cinv = 1.f / fmaxf(c, 1.f);
    }
    __syncthreads();
    if (t < HH) {
        float pv = p.bn[t], ci = sm.c1.cinv;
#pragma unroll
        for (int d = 0; d < NDD; d++) pv += sm.c1.s16[d] * ci * p.Wn[d * HH + t];
        sm.c1.pool[t] = pv;
    }
    __syncthreads();
    float a = 0.f;
#pragma unroll 4
    for (int k = kh * 64; k < kh * 64 + 64; k++)
        a += sm.c1.te[k] * p.Wt[k * HH + j] + sm.c1.pool[k] * p.Wc[k * HH + j];
    sm.c1.red[kh][j] = a;
    __syncthreads();
    if (t < HH)
        sm.c1.v2[t] = p.bt[t] + p.bc[t] + p.bn[t] + sm.c1.red[0][t] + sm.c1.red[1][t];
    __syncthreads();
    a = 0.f;
#pragma unroll 4
    for (int k = kh * 64; k < kh * 64 + 64; k++) a += sm.c1.v2[k] * p.Wc1[k * HH + j];
    sm.c1.red[kh][j] = a;
    __syncthreads();
    if (t < HH) p.c1g[g * HH + t] = sm.c1.red[0][t] + sm.c1.red[1][t];
}

// ---------- PH2: xw1 = (x @ W1p + c1[bm]) * dinv, 4 rows/block ----------
__device__ __forceinline__ void ph2(const Prm& p, SMem&, int b, int t) {
    int col = t & 127, rh = t >> 7;
    int r0 = b * 4 + rh * 2;
    const float* x0 = p.x + r0 * NDD;
    float acc0 = 0.f, acc1 = 0.f;
#pragma unroll
    for (int k = 0; k < NDD; k++) {
        float wv = p.W1p[k * HH + col];
        acc0 += x0[k] * wv;
        acc1 += x0[NDD + k] * wv;
    }
    int g0 = p.bm[r0], g1 = p.bm[r0 + 1];
    float d0 = rsqrtf((float)p.cnt[r0] + 1.f);
    float d1 = rsqrtf((float)p.cnt[r0 + 1] + 1.f);
    p.bufA[r0 * HH + col] = (acc0 + p.c1g[g0 * HH + col]) * d0;
    p.bufA[(r0 + 1) * HH + col] = (acc1 + p.c1g[g1 * HH + col]) * d1;
}

// ---------- gather helper: acc += sum of neighbor rows (float2 lane view) ----------
__device__ __forceinline__ void gather(const float2* __restrict__ xwp,
                                       const int* __restrict__ ci, int end, int l,
                                       float2& acc) {
    int e = 0;
    for (; e + 7 < end; e += 8) {
        int s0 = ci[e], s1 = ci[e + 1], s2 = ci[e + 2], s3 = ci[e + 3];
        int s4 = ci[e + 4], s5 = ci[e + 5], s6 = ci[e + 6], s7 = ci[e + 7];
        float2 v0 = xwp[s0 * 64 + l], v1 = xwp[s1 * 64 + l];
        float2 v2 = xwp[s2 * 64 + l], v3 = xwp[s3 * 64 + l];
        float2 v4 = xwp[s4 * 64 + l], v5 = xwp[s5 * 64 + l];
        float2 v6 = xwp[s6 * 64 + l], v7 = xwp[s7 * 64 + l];
        acc.x += ((v0.x + v1.x) + (v2.x + v3.x)) + ((v4.x + v5.x) + (v6.x + v7.x));
        acc.y += ((v0.y + v1.y) + (v2.y + v3.y)) + ((v4.y + v5.y) + (v6.y + v7.y));
    }
    for (; e + 3 < end; e += 4) {
        int s0 = ci[e], s1 = ci[e + 1], s2 = ci[e + 2], s3 = ci[e + 3];
        float2 v0 = xwp[s0 * 64 + l], v1 = xwp[s1 * 64 + l];
        float2 v2 = xwp[s2 * 64 + l], v3 = xwp[s3 * 64 + l];
        acc.x += (v0.x + v1.x) + (v2.x + v3.x);
        acc.y += (v0.y + v1.y) + (v2.y + v3.y);
    }
    for (; e < end; e++) {
        float2 v = xwp[ci[e] * 64 + l];
        acc.x += v.x;
        acc.y += v.y;
    }
}

// ---------- PH3: conv1 aggregate + fused gemm2 (Wc2 staged in 16KB quarters) ----------
__device__ __forceinline__ void ph3(const Prm& p, SMem& sm, int b, int t) {
    int w = t >> 6, l = t & 63;
    int dst = b * 4 + w;
    int deg = p.cnt[dst];
    float dd = rsqrtf((float)deg + 1.f);
    int end = deg < CAP ? deg : CAP;
    const float2* xwp = (const float2*)p.bufA;
    float2 acc = xwp[dst * 64 + l];  // self loop (pre-scaled in PH2)
    gather(xwp, p.col_idx + dst * CAP, end, l, acc);
    float2 h;
    h.x = fmaxf(dd * acc.x + p.b1[2 * l], 0.f);
    h.y = fmaxf(dd * acc.y + p.b1[2 * l + 1], 0.f);
    *(float2*)&sm.conv.hr[w][2 * l] = h;
    float2 o = {0.f, 0.f};
#pragma unroll
    for (int q = 0; q < 4; q++) {
        __syncthreads();  // hr ready (q0) / previous quarter's reads done
        const float4* s4 = (const float4*)(p.Wc2 + q * 32 * HH);
        float4* d4 = (float4*)sm.conv.wsm;
#pragma unroll
        for (int i = 0; i < 4; i++) d4[i * 256 + t] = s4[i * 256 + t];
        __syncthreads();
#pragma unroll 4
        for (int k = 0; k < 32; k++) {
            float hk = sm.conv.hr[w][q * 32 + k];
            float2 wv = *(const float2*)&sm.conv.wsm[k * HH + 2 * l];
            o.x += hk * wv.x;
            o.y += hk * wv.y;
        }
    }
    o.x *= dd;
    o.y *= dd;
    ((float2*)p.bufB)[dst * 64 + l] = o;
}

// ---------- PH4: conv2 aggregate + pred + sl/sr ----------
__device__ __forceinline__ void ph4(const Prm& p, SMem& sm, int b, int t) {
    int w = t >> 6, l = t & 63;
    int dst = b * 4 + w;
    int deg = p.cnt[dst];
    float dd = rsqrtf((float)deg + 1.f);
    int end = deg < CAP ? deg : CAP;
    const float2* xwp = (const float2*)p.bufB;
    float2 acc = xwp[dst * 64 + l];
    gather(xwp, p.col_idx + dst * CAP, end, l, acc);
    float2 h;
    h.x = fmaxf(dd * acc.x + p.b2[2 * l], 0.f);
    h.y = fmaxf(dd * acc.y + p.b2[2 * l + 1], 0.f);
    *(float2*)&sm.conv.hr[w][2 * l] = h;
    __syncthreads();
    {  // pred: c = l&15, partial pp = l>>4 over k in [32pp, 32pp+32)
        int c = l & 15, pp = l >> 4;
        float a = 0.f;
#pragma unroll 4
        for (int k = pp * 32; k < pp * 32 + 32; k++) a += sm.conv.hr[w][k] * p.Wo[k * NDD + c];
        a += __shfl_xor(a, 16);
        a += __shfl_xor(a, 32);
        if (pp == 0) p.out_pred[dst * NDD + c] = a + p.bo[c];
    }
    {  // sl/sr
        float h0 = sm.conv.hr[w][l], h1v = sm.conv.hr[w][64 + l];
        float pl = h0 * p.we[l] + h1v * p.we[64 + l];
        float pr = h0 * p.we[HH + l] + h1v * p.we[HH + 64 + l];
        for (int off = 32; off; off >>= 1) {
            pl += __shfl_down(pl, off);
            pr += __shfl_down(pr, off);
        }
        if (l == 0) {
            p.sl[dst] = pl;
            p.sr[dst] = pr;
        }
    }
}

// ---------- PH5: edge logits (2048 units over NBLK blocks) ----------
__device__ __forceinline__ void ph5(const Prm& p, SMem&, int b, int t) {
    float be = p.be[0];
    for (int u = b; u < NN / 2; u += NBLK) {
#pragma unroll
        for (int half = 0; half < 2; half++) {
            int r = half == 0 ? u : (NN - 2 - u);
            int off = r * (2 * NN - r - 1) / 2;  // < 2^23, fits int
            int len = NN - 1 - r;
            float s = p.sl[r] + be;
            const float* sp = p.sr + r + 1;
            float* op = p.out_edges + off;
            int hd = (4 - (off & 3)) & 3;
            if (hd > len) hd = len;
            if (t < hd) __builtin_nontemporal_store(s + sp[t], op + t);
            int body = (len - hd) >> 2;
            float* opb = op + hd;
            const float* spb = sp + hd;
            for (int i = t; i < body; i += 256) {
                int base = 4 * i;
                nt_f4 v;
                v.x = s + spb[base];
                v.y = s + spb[base + 1];
                v.z = s + spb[base + 2];
                v.w = s + spb[base + 3];
                __builtin_nontemporal_store(v, (nt_f4*)(opb + base));
            }
            int tail = hd + body * 4;
            int rem = len - tail;
            if (t < rem) __builtin_nontemporal_store(s + sp[tail + t], op + tail + t);
        }
    }
}

__global__ __launch_bounds__(256, 4) void k_mega(Prm p, int lo, int hi) {
    __shared__ SMem sm;
    int b = blockIdx.x, t = threadIdx.x;
    for (int ph = lo; ph <= hi; ++ph) {
        if (ph == 0) ph0(p, sm, b, t);
        else if (ph == 1) ph1(p, sm, b, t);
        else if (ph == 2) ph2(p, sm, b, t);
        else if (ph == 3) ph3(p, sm, b, t);
        else if (ph == 4) ph4(p, sm, b, t);
        else ph5(p, sm, b, t);
        if (ph < hi) cg::this_grid().sync();
    }
}

extern "C" void kernel_launch(void* const* d_in, const int* in_sizes, int n_in,
                              void* d_out, int out_size, void* d_ws, size_t ws_size,
                              hipStream_t stream) {
    Prm p;
    p.x = (const float*)d_in[0];
    p.e_src = (const int*)d_in[1];
    p.e_dst = p.e_src + EE;
    p.timestep = (const int*)d_in[2];
    p.bm = (const int*)d_in[3];
    p.nuc = (const int*)d_in[4];
    p.central = (const int*)d_in[5];
    p.backbone = (const int*)d_in[6];
    p.obj_x = (const float*)d_in[7];
    p.obj_pos = (const float*)d_in[8];
    p.obj_batch = (const int*)d_in[9];
    p.Wn = (const float*)d_in[10];
    p.bn = (const float*)d_in[11];
    p.Wc = (const float*)d_in[12];
    p.bc = (const float*)d_in[13];
    p.Wt = (const float*)d_in[14];
    p.bt = (const float*)d_in[15];
    p.Wc1 = (const float*)d_in[16];
    p.b1 = (const float*)d_in[17];
    p.Wc2 = (const float*)d_in[18];
    p.b2 = (const float*)d_in[19];
    p.Wo = (const float*)d_in[20];
    p.bo = (const float*)d_in[21];
    p.we = (const float*)d_in[22];
    p.be = (const float*)d_in[23];

    float* ws = (float*)d_ws;
    p.bufA = ws;                                  // N*H
    p.bufB = p.bufA + NN * HH;                    // N*H
    p.W1p = p.bufB + NN * HH;                     // 16*H
    p.c1g = p.W1p + NDD * HH;                     // G*H
    p.partial = p.c1g + GG * HH;                  // CBLK*G*16
    p.pcnt = p.partial + CBLK * GG * NDD;         // CBLK*G
    p.sl = p.pcnt + CBLK * GG;                    // N
    p.sr = p.sl + NN;                             // N
    p.cnt = (int*)(p.sr + NN);                    // N
    p.col_idx = p.cnt + NN;                       // N*CAP

    p.out_pred = (float*)d_out;
    p.out_edges = p.out_pred + NN * NDD;

    int lo = 0, hi = 5;
    void* args[] = {&p, &lo, &hi};
    hipError_t err = hipLaunchCooperativeKernel((void*)k_mega, dim3(NBLK), dim3(256),
                                                args, 0, stream);
    if (err != hipSuccess) {
        // fallback: one phase per launch (no grid.sync executed when lo==hi)
        for (int ph = 0; ph < 6; ph++) k_mega<<<NBLK, 256, 0, stream>>>(p, ph, ph);
    }
}

// Round 4
// 172.786 us; speedup vs baseline: 5.0555x; 5.0555x over previous
//
#include <hip/hip_runtime.h>

#define NN 4096
#define MM 8192
#define GG 8
#define HH 128
#define NDD 16
#define EE 131072
#define ZBLK 4             // cnt-zero blocks
#define CBLK 64            // cond partial blocks
#define COBJ (MM / CBLK)   // 128 objects per cond block
#define WBLK 8             // W1p gemm blocks (2 rows each)
#define SB2 32             // scatter blocks in k_mid (1024 thr each)
#define CAP 96             // padded CSR row capacity (verified: passes, max deg <= 96)

typedef float nt_f4 __attribute__((ext_vector_type(4)));

// ============ K1 front: zero cnt (0..3) | cond partials (4..67) | W1p (68..75) ============
__global__ __launch_bounds__(256) void k_front(
    const float* __restrict__ obj_x, const float* __restrict__ obj_pos,
    const int* __restrict__ nuc, const int* __restrict__ central,
    const int* __restrict__ backbone, const int* __restrict__ obj_batch,
    int* __restrict__ cnt, float* __restrict__ partial, float* __restrict__ pcnt,
    const float* __restrict__ Wn, const float* __restrict__ Wc1,
    float* __restrict__ W1p) {
    int b = blockIdx.x, t = threadIdx.x;
    if (b < ZBLK) {
        ((int4*)cnt)[b * 256 + t] = make_int4(0, 0, 0, 0);  // 4*256*4 = 4096 ints
        return;
    }
    if (b < ZBLK + CBLK) {
        int cb = b - ZBLK;
        __shared__ float ls[GG * NDD];
        __shared__ float lc[GG];
        if (t < GG * NDD) ls[t] = 0.f;
        if (t < GG) lc[t] = 0.f;
        __syncthreads();
        int d = t & 15, oi = t >> 4;
        int base = cb * COBJ;
#pragma unroll
        for (int pass = 0; pass < COBJ / 16; pass++) {
            int o = base + pass * 16 + oi;
            int nv = nuc[o];
            bool isb = (backbone[o] == 0);
            bool cond = (nv == 0) || ((central[o] != 0) && isb) || ((nv == 2) && isb);
            if (cond) {
                float v = (d < 13) ? obj_x[o * 13 + d] : obj_pos[o * 3 + (d - 13)];
                int g = obj_batch[o];
                atomicAdd(&ls[g * NDD + d], v);
                if (d == 0) atomicAdd(&lc[g], 1.f);
            }
        }
        __syncthreads();
        if (t < GG * NDD) partial[cb * (GG * NDD) + t] = ls[t];
        if (t < GG) pcnt[cb * GG + t] = lc[t];
        return;
    }
    // W1'[a][j] = sum_k Wn[a][k] * Wc1[k][j] -- 8 blocks, 2 rows each
    int wb = b - (ZBLK + CBLK);
    int j = t & 127, a = wb * 2 + (t >> 7);
    float acc = 0.f;
    for (int k = 0; k < HH; k++) acc += Wn[a * HH + k] * Wc1[k * HH + j];
    W1p[a * HH + j] = acc;
}

// ============ K2 mid: padded scatter (0..31) | redundant-c1 + xw1 (32..159). 1024 thr. ============
// xw = x @ W1p + c1[bm[row]]  (UNSCALED -- dinv applied in conv1's gather, so no cnt dep here)
__global__ __launch_bounds__(1024) void k_mid(
    const int* __restrict__ e_src, const int* __restrict__ e_dst,
    int* __restrict__ cnt, int* __restrict__ col_idx,
    const int* __restrict__ timestep, const float* __restrict__ partial,
    const float* __restrict__ pcnt, const float* __restrict__ Wn,
    const float* __restrict__ bn, const float* __restrict__ Wt,
    const float* __restrict__ bt, const float* __restrict__ Wc,
    const float* __restrict__ bc, const float* __restrict__ Wc1,
    const float* __restrict__ x, const float* __restrict__ W1p,
    const int* __restrict__ bm, float* __restrict__ xw) {
    int b = blockIdx.x, t = threadIdx.x;
    if (b < SB2) {
        int i4 = b * 1024 + t;  // 32 * 1024 = 32768 int4 = 131072 edges
        int4 d4 = ((const int4*)e_dst)[i4];
        int4 s4 = ((const int4*)e_src)[i4];
        int q;
        q = atomicAdd(&cnt[d4.x], 1); if (q < CAP) col_idx[d4.x * CAP + q] = s4.x;
        q = atomicAdd(&cnt[d4.y], 1); if (q < CAP) col_idx[d4.y * CAP + q] = s4.y;
        q = atomicAdd(&cnt[d4.z], 1); if (q < CAP) col_idx[d4.z * CAP + q] = s4.z;
        q = atomicAdd(&cnt[d4.w], 1); if (q < CAP) col_idx[d4.w * CAP + q] = s4.w;
        return;
    }
    int rb = b - SB2;
    int g = t >> 7, j = t & 127;
    __shared__ float s16[GG * NDD];
    __shared__ float cinv[GG];
    __shared__ float te[GG * HH];
    __shared__ float pool[GG * HH];
    __shared__ float v2[GG * HH];
    __shared__ float c1s[GG * HH];
    __shared__ float xt[32 * NDD];
    // phase 1: te (all), partial sums (t<128), counts, x tile (t>=512)
    {
        float tv = (float)timestep[g];
        float val;
        if (j < 64) {
            float f = expf(-logf(10000.f) * (float)j / 64.f);
            val = cosf(tv * f);
        } else {
            float f = expf(-logf(10000.f) * (float)(j - 64) / 64.f);
            val = sinf(tv * f);
        }
        te[t] = val;
    }
    if (t < GG * NDD) {
        float s = 0.f;
        for (int q = 0; q < CBLK; q++) s += partial[q * (GG * NDD) + t];
        s16[t] = s;
    } else if (t < GG * NDD + GG) {
        int gg = t - GG * NDD;
        float c = 0.f;
        for (int q = 0; q < CBLK; q++) c += pcnt[q * GG + gg];
        cinv[gg] = 1.f / fmaxf(c, 1.f);
    }
    if (t >= 512) xt[t - 512] = x[rb * 32 * NDD + (t - 512)];
    __syncthreads();
    // phase 2: pool = bn + mean(cond) @ Wn
    {
        float p = bn[j];
        float ci = cinv[g];
#pragma unroll
        for (int d = 0; d < NDD; d++) p += s16[g * NDD + d] * ci * Wn[d * HH + j];
        pool[t] = p;
    }
    __syncthreads();
    // phase 3: v2 = bt + bc + bn + te@Wt + pool@Wc
    {
        float acc = bt[j] + bc[j] + bn[j];
#pragma unroll 4
        for (int k = 0; k < HH; k++)
            acc += te[g * HH + k] * Wt[k * HH + j] + pool[g * HH + k] * Wc[k * HH + j];
        v2[t] = acc;
    }
    __syncthreads();
    // phase 4: c1 = v2 @ Wc1
    {
        float cc = 0.f;
#pragma unroll 4
        for (int k = 0; k < HH; k++) cc += v2[g * HH + k] * Wc1[k * HH + j];
        c1s[t] = cc;
    }
    __syncthreads();
    // phase 5: xw1 (32 rows) + add c1 (no dinv)
    {
        int col = j, rh = g;
        int r0 = rb * 32;
        float acc[4] = {0.f, 0.f, 0.f, 0.f};
#pragma unroll
        for (int k = 0; k < NDD; k++) {
            float wv = W1p[k * HH + col];
#pragma unroll
            for (int i = 0; i < 4; i++) acc[i] += xt[(rh * 4 + i) * NDD + k] * wv;
        }
#pragma unroll
        for (int i = 0; i < 4; i++) {
            int row = r0 + rh * 4 + i;
            xw[row * HH + col] = acc[i] + c1s[bm[row] * HH + col];
        }
    }
}

// ============ K3: conv1. 2 dst/block, 2 waves/dst (split gather) + gemm2 (Wc2 16KB quarters) ============
__global__ __launch_bounds__(256, 8) void k_conv1(
    const float* __restrict__ xw, const int* __restrict__ cnt,
    const int* __restrict__ col_idx, const float* __restrict__ b1,
    const float* __restrict__ Wc2, float* __restrict__ xw2) {
    int t = threadIdx.x;
    int w = t >> 6, l = t & 63;
    int d = w >> 1, half = w & 1;
    int dst = blockIdx.x * 2 + d;
    int deg = cnt[dst];
    float dd = rsqrtf((float)deg + 1.f);
    int end = deg < CAP ? deg : CAP;
    int mid = end >> 1;
    const float2* xwp = (const float2*)xw;
    const int* ci = col_idx + dst * CAP;
    float2 acc = {0.f, 0.f};
    if (half == 0) {  // self loop: dinv[dst] * xw[dst]
        float2 sv = xwp[dst * 64 + l];
        acc.x = dd * sv.x;
        acc.y = dd * sv.y;
    }
    int e = half ? mid : 0;
    int e1 = half ? end : mid;
    for (; e + 3 < e1; e += 4) {
        int s0 = ci[e], s1 = ci[e + 1], s2 = ci[e + 2], s3 = ci[e + 3];
        float r0 = rsqrtf((float)cnt[s0] + 1.f), r1 = rsqrtf((float)cnt[s1] + 1.f);
        float r2 = rsqrtf((float)cnt[s2] + 1.f), r3 = rsqrtf((float)cnt[s3] + 1.f);
        float2 v0 = xwp[s0 * 64 + l], v1 = xwp[s1 * 64 + l];
        float2 v2 = xwp[s2 * 64 + l], v3 = xwp[s3 * 64 + l];
        acc.x += (r0 * v0.x + r1 * v1.x) + (r2 * v2.x + r3 * v3.x);
        acc.y += (r0 * v0.y + r1 * v1.y) + (r2 * v2.y + r3 * v3.y);
    }
    for (; e < e1; e++) {
        int s = ci[e];
        float r = rsqrtf((float)cnt[s] + 1.f);
        float2 v = xwp[s * 64 + l];
        acc.x += r * v.x;
        acc.y += r * v.y;
    }
    __shared__ float hr[2][HH];
    __shared__ float2 part[2][64];
    __shared__ float wsm[32 * HH];  // 16 KB quarter of Wc2
    if (half == 1) part[d][l] = acc;
    __syncthreads();
    if (half == 0) {
        float2 pv = part[d][l];
        acc.x += pv.x;
        acc.y += pv.y;
        float2 h;
        h.x = fmaxf(dd * acc.x + b1[2 * l], 0.f);
        h.y = fmaxf(dd * acc.y + b1[2 * l + 1], 0.f);
        *(float2*)&hr[d][2 * l] = h;
    }
    // gemm2: o = h @ Wc2, k split across wave pair, Wc2 staged in quarters
    float2 o = {0.f, 0.f};
#pragma unroll
    for (int q = 0; q < 4; q++) {
        __syncthreads();  // hr ready (q0) / previous quarter reads done
        const float4* s4 = (const float4*)(Wc2 + q * 32 * HH);
        float4* d4 = (float4*)wsm;
#pragma unroll
        for (int i = 0; i < 4; i++) d4[i * 256 + t] = s4[i * 256 + t];
        __syncthreads();
#pragma unroll 4
        for (int k = 0; k < 16; k++) {
            int kk = half * 16 + k;  // row within quarter
            float hk = hr[d][q * 32 + kk];
            float2 wv = *(const float2*)&wsm[kk * HH + 2 * l];
            o.x += hk * wv.x;
            o.y += hk * wv.y;
        }
    }
    __syncthreads();  // part reuse safe
    if (half == 1) part[d][l] = o;
    __syncthreads();
    if (half == 0) {
        float2 pv = part[d][l];
        o.x = (o.x + pv.x) * dd;  // pre-scale output by dinv[dst] for conv2's gather
        o.y = (o.y + pv.y) * dd;
        ((float2*)xw2)[dst * 64 + l] = o;
    }
}

// ============ K4: conv2 (split gather, input pre-scaled) + pred + sl/sr ============
__global__ __launch_bounds__(256, 8) void k_conv2_head(
    const float* __restrict__ xw, const int* __restrict__ cnt,
    const int* __restrict__ col_idx, const float* __restrict__ b2,
    const float* __restrict__ Wo, const float* __restrict__ bo,
    const float* __restrict__ we, float* __restrict__ out_pred,
    float* __restrict__ sl, float* __restrict__ sr) {
    int t = threadIdx.x;
    int w = t >> 6, l = t & 63;
    int d = w >> 1, half = w & 1;
    int dst = blockIdx.x * 2 + d;
    int deg = cnt[dst];
    float dd = rsqrtf((float)deg + 1.f);
    int end = deg < CAP ? deg : CAP;
    int mid = end >> 1;
    const float2* xwp = (const float2*)xw;
    const int* ci = col_idx + dst * CAP;
    float2 acc = {0.f, 0.f};
    if (half == 0) acc = xwp[dst * 64 + l];  // self loop (pre-scaled)
    int e = half ? mid : 0;
    int e1 = half ? end : mid;
    for (; e + 3 < e1; e += 4) {
        int s0 = ci[e], s1 = ci[e + 1], s2 = ci[e + 2], s3 = ci[e + 3];
        float2 v0 = xwp[s0 * 64 + l], v1 = xwp[s1 * 64 + l];
        float2 v2 = xwp[s2 * 64 + l], v3 = xwp[s3 * 64 + l];
        acc.x += (v0.x + v1.x) + (v2.x + v3.x);
        acc.y += (v0.y + v1.y) + (v2.y + v3.y);
    }
    for (; e < e1; e++) {
        float2 v = xwp[ci[e] * 64 + l];
        acc.x += v.x;
        acc.y += v.y;
    }
    __shared__ float hr[2][HH];
    __shared__ float2 part[2][64];
    if (half == 1) part[d][l] = acc;
    __syncthreads();
    if (half == 0) {
        float2 pv = part[d][l];
        acc.x += pv.x;
        acc.y += pv.y;
        float2 h;
        h.x = fmaxf(dd * acc.x + b2[2 * l], 0.f);
        h.y = fmaxf(dd * acc.y + b2[2 * l + 1], 0.f);
        *(float2*)&hr[d][2 * l] = h;
    }
    __syncthreads();
    if (half == 0) {
        // pred: c = l&15, partial pp = l>>4 over k in [32pp, 32pp+32)
        int c = l & 15, pp = l >> 4;
        float a = 0.f;
#pragma unroll 4
        for (int k = pp * 32; k < pp * 32 + 32; k++) a += hr[d][k] * Wo[k * NDD + c];
        a += __shfl_xor(a, 16);
        a += __shfl_xor(a, 32);
        if (pp == 0) out_pred[dst * NDD + c] = a + bo[c];
    } else {
        // sl/sr
        float h0 = hr[d][l], h1v = hr[d][64 + l];
        float pl = h0 * we[l] + h1v * we[64 + l];
        float pr = h0 * we[HH + l] + h1v * we[HH + 64 + l];
        for (int off = 32; off; off >>= 1) {
            pl += __shfl_down(pl, off);
            pr += __shfl_down(pr, off);
        }
        if (l == 0) {
            sl[dst] = pl;
            sr[dst] = pr;
        }
    }
}

// ============ K5: edge logits, nontemporal stores, rows b and NN-2-b per block ============
__global__ __launch_bounds__(256) void k_edges(const float* __restrict__ sl,
                                               const float* __restrict__ sr,
                                               const float* __restrict__ be_p,
                                               float* __restrict__ out) {
    int b = blockIdx.x, t = threadIdx.x;
    float be = be_p[0];
#pragma unroll
    for (int half = 0; half < 2; half++) {
        int r = half == 0 ? b : (NN - 2 - b);
        int off = r * (2 * NN - r - 1) / 2;  // < 2^23, fits int
        int len = NN - 1 - r;
        float s = sl[r] + be;
        const float* sp = sr + r + 1;
        float* op = out + off;
        int hd = (4 - (off & 3)) & 3;
        if (hd > len) hd = len;
        if (t < hd) __builtin_nontemporal_store(s + sp[t], op + t);
        int body = (len - hd) >> 2;
        float* opb = op + hd;
        const float* spb = sp + hd;
        for (int i = t; i < body; i += 256) {
            int base = 4 * i;
            nt_f4 v;
            v.x = s + spb[base];
            v.y = s + spb[base + 1];
            v.z = s + spb[base + 2];
            v.w = s + spb[base + 3];
            __builtin_nontemporal_store(v, (nt_f4*)(opb + base));
        }
        int tail = hd + body * 4;
        int rem = len - tail;
        if (t < rem) __builtin_nontemporal_store(s + sp[tail + t], op + tail + t);
    }
}

extern "C" void kernel_launch(void* const* d_in, const int* in_sizes, int n_in,
                              void* d_out, int out_size, void* d_ws, size_t ws_size,
                              hipStream_t stream) {
    const float* x = (const float*)d_in[0];
    const int* e_src = (const int*)d_in[1];
    const int* e_dst = e_src + EE;
    const int* timestep = (const int*)d_in[2];
    const int* batch_map = (const int*)d_in[3];
    const int* nuc = (const int*)d_in[4];
    const int* central = (const int*)d_in[5];
    const int* backbone = (const int*)d_in[6];
    const float* obj_x = (const float*)d_in[7];
    const float* obj_pos = (const float*)d_in[8];
    const int* obj_batch = (const int*)d_in[9];
    const float* W_node = (const float*)d_in[10];
    const float* b_node = (const float*)d_in[11];
    const float* W_cond = (const float*)d_in[12];
    const float* b_cond = (const float*)d_in[13];
    const float* W_time = (const float*)d_in[14];
    const float* b_time = (const float*)d_in[15];
    const float* W_conv1 = (const float*)d_in[16];
    const float* b_conv1 = (const float*)d_in[17];
    const float* W_conv2 = (const float*)d_in[18];
    const float* b_conv2 = (const float*)d_in[19];
    const float* W_out = (const float*)d_in[20];
    const float* b_out = (const float*)d_in[21];
    const float* w_edge = (const float*)d_in[22];
    const float* b_edge = (const float*)d_in[23];

    // workspace
    float* ws = (float*)d_ws;
    float* bufA = ws;                        // N*H (xw1, unscaled)
    float* bufB = bufA + NN * HH;            // N*H (xw2, pre-scaled)
    float* W1p = bufB + NN * HH;             // 16*H
    float* partial = W1p + NDD * HH;         // CBLK*G*16
    float* pcnt = partial + CBLK * GG * NDD; // CBLK*G
    float* sl = pcnt + CBLK * GG;            // N
    float* sr = sl + NN;                     // N
    int* cnt = (int*)(sr + NN);              // N (degree counters)
    int* col_idx = cnt + NN;                 // N*CAP padded CSR

    float* out_pred = (float*)d_out;
    float* out_edges = out_pred + NN * NDD;

    // K1: zero cnt + cond partials + W1p
    k_front<<<ZBLK + CBLK + WBLK, 256, 0, stream>>>(obj_x, obj_pos, nuc, central,
                                                    backbone, obj_batch, cnt, partial,
                                                    pcnt, W_node, W_conv1, W1p);
    // K2: padded scatter + redundant-c1 + xw1 (unscaled)
    k_mid<<<SB2 + NN / 32, 1024, 0, stream>>>(e_src, e_dst, cnt, col_idx, timestep,
                                              partial, pcnt, W_node, b_node, W_time,
                                              b_time, W_cond, b_cond, W_conv1, x,
                                              W1p, batch_map, bufA);
    // K3: conv1 (gather-side dinv) + gemm2 -> bufB (pre-scaled)
    k_conv1<<<NN / 2, 256, 0, stream>>>(bufA, cnt, col_idx, b_conv1, W_conv2, bufB);
    // K4: conv2 + pred + sl/sr
    k_conv2_head<<<NN / 2, 256, 0, stream>>>(bufB, cnt, col_idx, b_conv2, W_out,
                                             b_out, w_edge, out_pred, sl, sr);
    // K5: edge logits
    k_edges<<<NN / 2, 256, 0, stream>>>(sl, sr, b_edge, out_edges);
}

// Round 5
// 169.855 us; speedup vs baseline: 5.1427x; 1.0173x over previous
//
#include <hip/hip_runtime.h>

#define NN 4096
#define MM 8192
#define GG 8
#define HH 128
#define NDD 16
#define EE 131072
#define ZBLK 4             // cnt-zero blocks
#define CBLK 64            // cond partial blocks
#define COBJ (MM / CBLK)   // 128 objects per cond block
#define WBLK 8             // W1p gemm blocks (2 rows each)
#define SB2 32             // scatter blocks in k_mid (1024 thr each)
#define CAP 96             // padded CSR row capacity (verified: passes, max deg <= 96)

typedef float nt_f4 __attribute__((ext_vector_type(4)));

// ============ K1 front: zero cnt (0..3) | cond partials (4..67) | W1p (68..75) ============
__global__ __launch_bounds__(256) void k_front(
    const float* __restrict__ obj_x, const float* __restrict__ obj_pos,
    const int* __restrict__ nuc, const int* __restrict__ central,
    const int* __restrict__ backbone, const int* __restrict__ obj_batch,
    int* __restrict__ cnt, float* __restrict__ partial, float* __restrict__ pcnt,
    const float* __restrict__ Wn, const float* __restrict__ Wc1,
    float* __restrict__ W1p) {
    int b = blockIdx.x, t = threadIdx.x;
    if (b < ZBLK) {
        ((int4*)cnt)[b * 256 + t] = make_int4(0, 0, 0, 0);  // 4*256*4 = 4096 ints
        return;
    }
    if (b < ZBLK + CBLK) {
        int cb = b - ZBLK;
        __shared__ float ls[GG * NDD];
        __shared__ float lc[GG];
        if (t < GG * NDD) ls[t] = 0.f;
        if (t < GG) lc[t] = 0.f;
        __syncthreads();
        int d = t & 15, oi = t >> 4;
        int base = cb * COBJ;
#pragma unroll
        for (int pass = 0; pass < COBJ / 16; pass++) {
            int o = base + pass * 16 + oi;
            int nv = nuc[o];
            bool isb = (backbone[o] == 0);
            bool cond = (nv == 0) || ((central[o] != 0) && isb) || ((nv == 2) && isb);
            if (cond) {
                float v = (d < 13) ? obj_x[o * 13 + d] : obj_pos[o * 3 + (d - 13)];
                int g = obj_batch[o];
                atomicAdd(&ls[g * NDD + d], v);
                if (d == 0) atomicAdd(&lc[g], 1.f);
            }
        }
        __syncthreads();
        if (t < GG * NDD) partial[cb * (GG * NDD) + t] = ls[t];
        if (t < GG) pcnt[cb * GG + t] = lc[t];
        return;
    }
    // W1'[a][j] = sum_k Wn[a][k] * Wc1[k][j] -- 8 blocks, 2 rows each, 2 accumulators
    int wb = b - (ZBLK + CBLK);
    int j = t & 127, a = wb * 2 + (t >> 7);
    float a0 = 0.f, a1 = 0.f;
    for (int k = 0; k < HH; k += 2) {
        a0 += Wn[a * HH + k] * Wc1[k * HH + j];
        a1 += Wn[a * HH + k + 1] * Wc1[(k + 1) * HH + j];
    }
    W1p[a * HH + j] = a0 + a1;
}

// ============ K2 mid: padded scatter (0..31) | redundant-c1 + xw1 (32..159). 1024 thr. ============
// xw = x @ W1p + c1[bm[row]]  (UNSCALED -- dinv applied in conv1's gather)
__global__ __launch_bounds__(1024) void k_mid(
    const int* __restrict__ e_src, const int* __restrict__ e_dst,
    int* __restrict__ cnt, int* __restrict__ col_idx,
    const int* __restrict__ timestep, const float* __restrict__ partial,
    const float* __restrict__ pcnt, const float* __restrict__ Wn,
    const float* __restrict__ bn, const float* __restrict__ Wt,
    const float* __restrict__ bt, const float* __restrict__ Wc,
    const float* __restrict__ bc, const float* __restrict__ Wc1,
    const float* __restrict__ x, const float* __restrict__ W1p,
    const int* __restrict__ bm, float* __restrict__ xw) {
    int b = blockIdx.x, t = threadIdx.x;
    if (b < SB2) {
        int i4 = b * 1024 + t;  // 32 * 1024 = 32768 int4 = 131072 edges
        int4 d4 = ((const int4*)e_dst)[i4];
        int4 s4 = ((const int4*)e_src)[i4];
        int q;
        q = atomicAdd(&cnt[d4.x], 1); if (q < CAP) col_idx[d4.x * CAP + q] = s4.x;
        q = atomicAdd(&cnt[d4.y], 1); if (q < CAP) col_idx[d4.y * CAP + q] = s4.y;
        q = atomicAdd(&cnt[d4.z], 1); if (q < CAP) col_idx[d4.z * CAP + q] = s4.z;
        q = atomicAdd(&cnt[d4.w], 1); if (q < CAP) col_idx[d4.w * CAP + q] = s4.w;
        return;
    }
    int rb = b - SB2;
    int g = t >> 7, j = t & 127;
    __shared__ float s16[GG * NDD];
    __shared__ float cinv[GG];
    __shared__ float te[GG * HH];
    __shared__ float pool[GG * HH];
    __shared__ float v2[GG * HH];
    __shared__ float c1s[GG * HH];
    __shared__ float xt[32 * NDD];
    // phase 1: te (all), partial sums (t<128), counts, x tile (t>=512)
    {
        float tv = (float)timestep[g];
        float val;
        if (j < 64) {
            float f = expf(-logf(10000.f) * (float)j / 64.f);
            val = cosf(tv * f);
        } else {
            float f = expf(-logf(10000.f) * (float)(j - 64) / 64.f);
            val = sinf(tv * f);
        }
        te[t] = val;
    }
    if (t < GG * NDD) {
        float s = 0.f;
        for (int q = 0; q < CBLK; q++) s += partial[q * (GG * NDD) + t];
        s16[t] = s;
    } else if (t < GG * NDD + GG) {
        int gg = t - GG * NDD;
        float c = 0.f;
        for (int q = 0; q < CBLK; q++) c += pcnt[q * GG + gg];
        cinv[gg] = 1.f / fmaxf(c, 1.f);
    }
    if (t >= 512) xt[t - 512] = x[rb * 32 * NDD + (t - 512)];
    __syncthreads();
    // phase 2: pool = bn + mean(cond) @ Wn
    {
        float p = bn[j];
        float ci = cinv[g];
#pragma unroll
        for (int d = 0; d < NDD; d++) p += s16[g * NDD + d] * ci * Wn[d * HH + j];
        pool[t] = p;
    }
    __syncthreads();
    // phase 3: v2 = bt + bc + bn + te@Wt + pool@Wc  (4 accumulators: break serial chain)
    {
        const float* teg = te + g * HH;
        const float* poolg = pool + g * HH;
        float a0 = 0.f, a1 = 0.f, a2 = 0.f, a3 = 0.f;
        for (int k = 0; k < HH; k += 4) {
            a0 += teg[k] * Wt[k * HH + j] + poolg[k] * Wc[k * HH + j];
            a1 += teg[k + 1] * Wt[(k + 1) * HH + j] + poolg[k + 1] * Wc[(k + 1) * HH + j];
            a2 += teg[k + 2] * Wt[(k + 2) * HH + j] + poolg[k + 2] * Wc[(k + 2) * HH + j];
            a3 += teg[k + 3] * Wt[(k + 3) * HH + j] + poolg[k + 3] * Wc[(k + 3) * HH + j];
        }
        v2[t] = bt[j] + bc[j] + bn[j] + ((a0 + a1) + (a2 + a3));
    }
    __syncthreads();
    // phase 4: c1 = v2 @ Wc1  (4 accumulators)
    {
        const float* v2g = v2 + g * HH;
        float a0 = 0.f, a1 = 0.f, a2 = 0.f, a3 = 0.f;
        for (int k = 0; k < HH; k += 4) {
            a0 += v2g[k] * Wc1[k * HH + j];
            a1 += v2g[k + 1] * Wc1[(k + 1) * HH + j];
            a2 += v2g[k + 2] * Wc1[(k + 2) * HH + j];
            a3 += v2g[k + 3] * Wc1[(k + 3) * HH + j];
        }
        c1s[t] = (a0 + a1) + (a2 + a3);
    }
    __syncthreads();
    // phase 5: xw1 (32 rows) + add c1 (no dinv)
    {
        int col = j, rh = g;
        int r0 = rb * 32;
        float acc[4] = {0.f, 0.f, 0.f, 0.f};
#pragma unroll
        for (int k = 0; k < NDD; k++) {
            float wv = W1p[k * HH + col];
#pragma unroll
            for (int i = 0; i < 4; i++) acc[i] += xt[(rh * 4 + i) * NDD + k] * wv;
        }
#pragma unroll
        for (int i = 0; i < 4; i++) {
            int row = r0 + rh * 4 + i;
            xw[row * HH + col] = acc[i] + c1s[bm[row] * HH + col];
        }
    }
}

// ============ K3: conv1. 8 dst/block, 1 wave/dst + gemm2 (Wc2 in 16KB quarters, 8x reuse) ============
__global__ __launch_bounds__(512, 2) void k_conv1(
    const float* __restrict__ xw, const int* __restrict__ cnt,
    const int* __restrict__ col_idx, const float* __restrict__ b1,
    const float* __restrict__ Wc2, float* __restrict__ xw2) {
    int t = threadIdx.x;
    int w = t >> 6, l = t & 63;
    int dst = blockIdx.x * 8 + w;
    int deg = cnt[dst];
    float dd = rsqrtf((float)deg + 1.f);
    int end = deg < CAP ? deg : CAP;
    const float2* xwp = (const float2*)xw;
    const int* ci = col_idx + dst * CAP;
    float2 sv = xwp[dst * 64 + l];
    float2 acc;
    acc.x = dd * sv.x;  // self loop: dinv[dst] * xw[dst]
    acc.y = dd * sv.y;
    int e = 0;
    for (; e + 7 < end; e += 8) {
        int s0 = ci[e], s1 = ci[e + 1], s2 = ci[e + 2], s3 = ci[e + 3];
        int s4 = ci[e + 4], s5 = ci[e + 5], s6 = ci[e + 6], s7 = ci[e + 7];
        float r0 = rsqrtf((float)cnt[s0] + 1.f), r1 = rsqrtf((float)cnt[s1] + 1.f);
        float r2 = rsqrtf((float)cnt[s2] + 1.f), r3 = rsqrtf((float)cnt[s3] + 1.f);
        float r4 = rsqrtf((float)cnt[s4] + 1.f), r5 = rsqrtf((float)cnt[s5] + 1.f);
        float r6 = rsqrtf((float)cnt[s6] + 1.f), r7 = rsqrtf((float)cnt[s7] + 1.f);
        float2 v0 = xwp[s0 * 64 + l], v1 = xwp[s1 * 64 + l];
        float2 v2 = xwp[s2 * 64 + l], v3 = xwp[s3 * 64 + l];
        float2 v4 = xwp[s4 * 64 + l], v5 = xwp[s5 * 64 + l];
        float2 v6 = xwp[s6 * 64 + l], v7 = xwp[s7 * 64 + l];
        acc.x += ((r0 * v0.x + r1 * v1.x) + (r2 * v2.x + r3 * v3.x)) +
                 ((r4 * v4.x + r5 * v5.x) + (r6 * v6.x + r7 * v7.x));
        acc.y += ((r0 * v0.y + r1 * v1.y) + (r2 * v2.y + r3 * v3.y)) +
                 ((r4 * v4.y + r5 * v5.y) + (r6 * v6.y + r7 * v7.y));
    }
    for (; e < end; e++) {
        int s = ci[e];
        float r = rsqrtf((float)cnt[s] + 1.f);
        float2 v = xwp[s * 64 + l];
        acc.x += r * v.x;
        acc.y += r * v.y;
    }
    __shared__ float hr[8][HH];
    __shared__ float wsm[32 * HH];  // 16 KB quarter of Wc2
    {
        float2 h;
        h.x = fmaxf(dd * acc.x + b1[2 * l], 0.f);
        h.y = fmaxf(dd * acc.y + b1[2 * l + 1], 0.f);
        *(float2*)&hr[w][2 * l] = h;  // own-wave write, own-wave read: no block sync needed
    }
    // gemm2: o = h @ Wc2, Wc2 staged in quarters (2 accumulator pairs: break serial chain)
    float ox0 = 0.f, ox1 = 0.f, oy0 = 0.f, oy1 = 0.f;
#pragma unroll
    for (int q = 0; q < 4; q++) {
        __syncthreads();  // previous quarter's reads done
        const float4* s4p = (const float4*)(Wc2 + q * 32 * HH);
        float4* d4p = (float4*)wsm;
#pragma unroll
        for (int i = 0; i < 2; i++) d4p[i * 512 + t] = s4p[i * 512 + t];
        __syncthreads();  // quarter staged
#pragma unroll 4
        for (int k = 0; k < 16; k++) {
            float h0 = hr[w][q * 32 + 2 * k];
            float h1 = hr[w][q * 32 + 2 * k + 1];
            float2 w0 = *(const float2*)&wsm[(2 * k) * HH + 2 * l];
            float2 w1 = *(const float2*)&wsm[(2 * k + 1) * HH + 2 * l];
            ox0 += h0 * w0.x;
            oy0 += h0 * w0.y;
            ox1 += h1 * w1.x;
            oy1 += h1 * w1.y;
        }
    }
    float2 o;
    o.x = (ox0 + ox1) * dd;  // pre-scale output by dinv[dst] for conv2's gather
    o.y = (oy0 + oy1) * dd;
    ((float2*)xw2)[dst * 64 + l] = o;
}

// ============ K4: conv2 (input pre-scaled, 1 wave/dst) + pred + sl/sr ============
__global__ __launch_bounds__(256) void k_conv2_head(
    const float* __restrict__ xw, const int* __restrict__ cnt,
    const int* __restrict__ col_idx, const float* __restrict__ b2,
    const float* __restrict__ Wo, const float* __restrict__ bo,
    const float* __restrict__ we, float* __restrict__ out_pred,
    float* __restrict__ sl, float* __restrict__ sr) {
    int t = threadIdx.x;
    int w = t >> 6, l = t & 63;
    int dst = blockIdx.x * 4 + w;
    int deg = cnt[dst];
    float dd = rsqrtf((float)deg + 1.f);
    int end = deg < CAP ? deg : CAP;
    const float2* xwp = (const float2*)xw;
    const int* ci = col_idx + dst * CAP;
    float2 acc = xwp[dst * 64 + l];  // self loop (pre-scaled)
    int e = 0;
    for (; e + 7 < end; e += 8) {
        int s0 = ci[e], s1 = ci[e + 1], s2 = ci[e + 2], s3 = ci[e + 3];
        int s4 = ci[e + 4], s5 = ci[e + 5], s6 = ci[e + 6], s7 = ci[e + 7];
        float2 v0 = xwp[s0 * 64 + l], v1 = xwp[s1 * 64 + l];
        float2 v2 = xwp[s2 * 64 + l], v3 = xwp[s3 * 64 + l];
        float2 v4 = xwp[s4 * 64 + l], v5 = xwp[s5 * 64 + l];
        float2 v6 = xwp[s6 * 64 + l], v7 = xwp[s7 * 64 + l];
        acc.x += ((v0.x + v1.x) + (v2.x + v3.x)) + ((v4.x + v5.x) + (v6.x + v7.x));
        acc.y += ((v0.y + v1.y) + (v2.y + v3.y)) + ((v4.y + v5.y) + (v6.y + v7.y));
    }
    for (; e + 3 < end; e += 4) {
        int s0 = ci[e], s1 = ci[e + 1], s2 = ci[e + 2], s3 = ci[e + 3];
        float2 v0 = xwp[s0 * 64 + l], v1 = xwp[s1 * 64 + l];
        float2 v2 = xwp[s2 * 64 + l], v3 = xwp[s3 * 64 + l];
        acc.x += (v0.x + v1.x) + (v2.x + v3.x);
        acc.y += (v0.y + v1.y) + (v2.y + v3.y);
    }
    for (; e < end; e++) {
        float2 v = xwp[ci[e] * 64 + l];
        acc.x += v.x;
        acc.y += v.y;
    }
    float2 h;
    h.x = fmaxf(dd * acc.x + b2[2 * l], 0.f);
    h.y = fmaxf(dd * acc.y + b2[2 * l + 1], 0.f);
    __shared__ float hr[4][HH];
    *(float2*)&hr[w][2 * l] = h;
    __syncthreads();
    // pred: c = l&15, partial pp = l>>4 over k in [32pp, 32pp+32)
    {
        int c = l & 15, pp = l >> 4;
        float a0 = 0.f, a1 = 0.f;
#pragma unroll 8
        for (int k = pp * 32; k < pp * 32 + 32; k += 2) {
            a0 += hr[w][k] * Wo[k * NDD + c];
            a1 += hr[w][k + 1] * Wo[(k + 1) * NDD + c];
        }
        float a = a0 + a1;
        a += __shfl_xor(a, 16);
        a += __shfl_xor(a, 32);
        if (pp == 0) out_pred[dst * NDD + c] = a + bo[c];
    }
    // sl/sr
    {
        float h0 = hr[w][l], h1v = hr[w][64 + l];
        float pl = h0 * we[l] + h1v * we[64 + l];
        float pr = h0 * we[HH + l] + h1v * we[HH + 64 + l];
        for (int off = 32; off; off >>= 1) {
            pl += __shfl_down(pl, off);
            pr += __shfl_down(pr, off);
        }
        if (l == 0) {
            sl[dst] = pl;
            sr[dst] = pr;
        }
    }
}

// ============ K5: edge logits, nontemporal stores, rows b and NN-2-b per block ============
__global__ __launch_bounds__(256) void k_edges(const float* __restrict__ sl,
                                               const float* __restrict__ sr,
                                               const float* __restrict__ be_p,
                                               float* __restrict__ out) {
    int b = blockIdx.x, t = threadIdx.x;
    float be = be_p[0];
#pragma unroll
    for (int half = 0; half < 2; half++) {
        int r = half == 0 ? b : (NN - 2 - b);
        int off = r * (2 * NN - r - 1) / 2;  // < 2^23, fits int
        int len = NN - 1 - r;
        float s = sl[r] + be;
        const float* sp = sr + r + 1;
        float* op = out + off;
        int hd = (4 - (off & 3)) & 3;
        if (hd > len) hd = len;
        if (t < hd) __builtin_nontemporal_store(s + sp[t], op + t);
        int body = (len - hd) >> 2;
        float* opb = op + hd;
        const float* spb = sp + hd;
        for (int i = t; i < body; i += 256) {
            int base = 4 * i;
            nt_f4 v;
            v.x = s + spb[base];
            v.y = s + spb[base + 1];
            v.z = s + spb[base + 2];
            v.w = s + spb[base + 3];
            __builtin_nontemporal_store(v, (nt_f4*)(opb + base));
        }
        int tail = hd + body * 4;
        int rem = len - tail;
        if (t < rem) __builtin_nontemporal_store(s + sp[tail + t], op + tail + t);
    }
}

extern "C" void kernel_launch(void* const* d_in, const int* in_sizes, int n_in,
                              void* d_out, int out_size, void* d_ws, size_t ws_size,
                              hipStream_t stream) {
    const float* x = (const float*)d_in[0];
    const int* e_src = (const int*)d_in[1];
    const int* e_dst = e_src + EE;
    const int* timestep = (const int*)d_in[2];
    const int* batch_map = (const int*)d_in[3];
    const int* nuc = (const int*)d_in[4];
    const int* central = (const int*)d_in[5];
    const int* backbone = (const int*)d_in[6];
    const float* obj_x = (const float*)d_in[7];
    const float* obj_pos = (const float*)d_in[8];
    const int* obj_batch = (const int*)d_in[9];
    const float* W_node = (const float*)d_in[10];
    const float* b_node = (const float*)d_in[11];
    const float* W_cond = (const float*)d_in[12];
    const float* b_cond = (const float*)d_in[13];
    const float* W_time = (const float*)d_in[14];
    const float* b_time = (const float*)d_in[15];
    const float* W_conv1 = (const float*)d_in[16];
    const float* b_conv1 = (const float*)d_in[17];
    const float* W_conv2 = (const float*)d_in[18];
    const float* b_conv2 = (const float*)d_in[19];
    const float* W_out = (const float*)d_in[20];
    const float* b_out = (const float*)d_in[21];
    const float* w_edge = (const float*)d_in[22];
    const float* b_edge = (const float*)d_in[23];

    // workspace
    float* ws = (float*)d_ws;
    float* bufA = ws;                        // N*H (xw1, unscaled)
    float* bufB = bufA + NN * HH;            // N*H (xw2, pre-scaled)
    float* W1p = bufB + NN * HH;             // 16*H
    float* partial = W1p + NDD * HH;         // CBLK*G*16
    float* pcnt = partial + CBLK * GG * NDD; // CBLK*G
    float* sl = pcnt + CBLK * GG;            // N
    float* sr = sl + NN;                     // N
    int* cnt = (int*)(sr + NN);              // N (degree counters)
    int* col_idx = cnt + NN;                 // N*CAP padded CSR

    float* out_pred = (float*)d_out;
    float* out_edges = out_pred + NN * NDD;

    // K1: zero cnt + cond partials + W1p
    k_front<<<ZBLK + CBLK + WBLK, 256, 0, stream>>>(obj_x, obj_pos, nuc, central,
                                                    backbone, obj_batch, cnt, partial,
                                                    pcnt, W_node, W_conv1, W1p);
    // K2: padded scatter + redundant-c1 + xw1 (unscaled)
    k_mid<<<SB2 + NN / 32, 1024, 0, stream>>>(e_src, e_dst, cnt, col_idx, timestep,
                                              partial, pcnt, W_node, b_node, W_time,
                                              b_time, W_cond, b_cond, W_conv1, x,
                                              W1p, batch_map, bufA);
    // K3: conv1 (gather-side dinv) + gemm2 -> bufB (pre-scaled)
    k_conv1<<<NN / 8, 512, 0, stream>>>(bufA, cnt, col_idx, b_conv1, W_conv2, bufB);
    // K4: conv2 + pred + sl/sr
    k_conv2_head<<<NN / 4, 256, 0, stream>>>(bufB, cnt, col_idx, b_conv2, W_out,
                                             b_out, w_edge, out_pred, sl, sr);
    // K5: edge logits
    k_edges<<<NN / 2, 256, 0, stream>>>(sl, sr, b_edge, out_edges);
}